// Round 7
// baseline (435.646 us; speedup 1.0000x reference)
//
#include <hip/hip_runtime.h>
#include <math.h>

typedef __bf16 bf16;
typedef __bf16 bf16x8 __attribute__((ext_vector_type(8)));
typedef float f32x4 __attribute__((ext_vector_type(4)));

#define MFMA16(a,b,c) __builtin_amdgcn_mfma_f32_16x16x32_bf16((a),(b),(c),0,0,0)

#define D 256
#define H 4
#define A 32
#define P 4
#define HA 128
#define RHID 64
#define ROWS 64
#define NROWS_TOT 262144
#define SCALE_F 0.17677669529663687f

// ws offsets in bf16 elements
#define OFF_Q  0
#define OFF_F  32768
#define OFF_G1 65536
#define OFF_G2 81920
#define OFF_O  98304
#define NPACK  102400

__device__ __forceinline__ float fast_exp(float x) { return __expf(x); }
__device__ __forceinline__ float fast_rcp(float x) { return __builtin_amdgcn_rcpf(x); }

// ---------------- weight prepack: f32 -> bf16 in MFMA B-fragment order ----------------
// B-fragment for 16x16x32: lane l holds col n = l&15, k = (l>>4)*8 + j (j=0..7, contiguous)
__global__ __launch_bounds__(256)
void prep_kernel(const float* __restrict__ Wq, const float* __restrict__ Wf,
                 const float* __restrict__ Wg1, const float* __restrict__ Wg2,
                 const float* __restrict__ Wo, bf16* __restrict__ ws)
{
  int i = blockIdx.x * 256 + threadIdx.x;
  if (i >= NPACK) return;
  float v;
  if (i < OFF_F) {              // packQ [h(4)][ks(8)][nt(2)][l(64)][j(8)], K=256,N=32 per head
    int j = i & 7, l = (i >> 3) & 63, nt = (i >> 9) & 1, ks = (i >> 10) & 7, h = i >> 13;
    int k = ks * 32 + (l >> 4) * 8 + j, n = nt * 16 + (l & 15);
    v = Wq[(h * 256 + k) * 32 + n];
  } else if (i < OFF_G1) {      // packF [ks(4)][gnt(16)][l][j], K=128,N=256
    int ii = i - OFF_F;
    int j = ii & 7, l = (ii >> 3) & 63, g = (ii >> 9) & 15, ks = ii >> 13;
    int k = ks * 32 + (l >> 4) * 8 + j, n = g * 16 + (l & 15);
    v = Wf[k * 256 + n];
  } else if (i < OFF_G2) {      // packG1 [ks(8)][nt(4)][l][j], K=256,N=64 (row 256 added via s_wg1d)
    int ii = i - OFF_G1;
    int j = ii & 7, l = (ii >> 3) & 63, nt = (ii >> 9) & 3, ks = ii >> 11;
    int k = ks * 32 + (l >> 4) * 8 + j, n = nt * 16 + (l & 15);
    v = Wg1[k * 64 + n];
  } else if (i < OFF_O) {       // packG2 [ks(2)][gnt(16)][l][j], K=64,N=256
    int ii = i - OFF_G2;
    int j = ii & 7, l = (ii >> 3) & 63, g = (ii >> 9) & 15, ks = ii >> 13;
    int k = ks * 32 + (l >> 4) * 8 + j, n = g * 16 + (l & 15);
    v = Wg2[k * 256 + n];
  } else {                      // packO [h(4)][nt(2)][l][j], K=32,N=32 per head
    int ii = i - OFF_O;
    int j = ii & 7, l = (ii >> 3) & 63, nt = (ii >> 9) & 1, h = ii >> 10;
    int k = (l >> 4) * 8 + j, n = nt * 16 + (l & 15);
    v = Wo[(h * 32 + k) * 32 + n];
  }
  ws[i] = (bf16)v;
}

// ---------------- fused main kernel: wave-independent, ZERO inter-phase barriers ----------------
// Each wave owns 16 rows end-to-end; private 8KB LDS slice for fragment redistribution.
// __launch_bounds__(256,2): empirically the only setting where the compiler lands VGPR=128
// with no scratch spills (tighter bounds over-shrink to 84/64 VGPR and spill, R3/R6).
// VGPR=128 -> 4 waves/SIMD; LDS 40960x4 = full 160KiB pool -> 4 blocks/CU.
__global__ __launch_bounds__(256, 2)
void faiia_kernel(const float* __restrict__ x, const float* __restrict__ mp,
    const float* __restrict__ bq, const float* __restrict__ pk,
    const float* __restrict__ pv, const float* __restrict__ imp,
    const float* __restrict__ fa, const float* __restrict__ ft,
    const float* __restrict__ bo, const float* __restrict__ lng,
    const float* __restrict__ lnb, const float* __restrict__ bfb,
    const float* __restrict__ Wg1, const float* __restrict__ bg1,
    const float* __restrict__ bg2, const float* __restrict__ lnFg,
    const float* __restrict__ lnFb, const bf16* __restrict__ ws,
    float* __restrict__ out)
{
  // per-wave 4096-bf16 slice, timeline:
  //  [0..4096) xfrag [ks8][64][8]          (GEMM1 A)
  //  [0..2048) q 16x128 swizzled           (after GEMM1)
  //  [2048..4096) attfrag [h4][64][8]      (Wo A)
  //  [0..2048) combfrag [ks4][64][8]       (GEMM2 A)
  //  [0..4096) opfrag [ks8][64][8]         (GEMM3 A)
  //  [0..1024) hfrag [ks2][64][8]          (GEMM4 A)
  __shared__ __attribute__((aligned(16))) bf16 s_regA[4 * 4096];
  __shared__ float s_pk[H*P*A], s_pv[H*P*A], s_imp[H*P], s_fa[H], s_ft[H];
  __shared__ bf16 s_bq[HA], s_bo[HA], s_lng[HA], s_lnb[HA];
  __shared__ bf16 s_bf[D], s_bg2[D], s_lnFg[D], s_lnFb[D];
  __shared__ float s_bg1[RHID], s_wg1d[RHID];
  __shared__ float s_diff[ROWS];

  const int t = threadIdx.x;
  const int lane = t & 63;
  const int w = t >> 6;
  const int lr = lane >> 4;       // row-group 0..3 (C-frag rows lr*4+r)
  const int lc = lane & 15;       // col-in-tile
  const int row0 = blockIdx.x * ROWS;
  const int arow0 = row0 + w * 16;          // this wave's absolute first row
  bf16* rA = s_regA + w * 4096;

  // ---- stage shared constants (block-wide) ----
  for (int i = t; i < H*P*A; i += 256) { s_pk[i] = pk[i]; s_pv[i] = pv[i]; }
  if (t < H*P) s_imp[t] = imp[t];
  if (t < H) { s_fa[t] = fa[t]; s_ft[t] = ft[t]; }
  if (t < HA) { s_bq[t] = (bf16)bq[t]; s_bo[t] = (bf16)bo[t];
                s_lng[t] = (bf16)lng[t]; s_lnb[t] = (bf16)lnb[t]; }
  s_bf[t] = (bf16)bfb[t]; s_bg2[t] = (bf16)bg2[t];
  s_lnFg[t] = (bf16)lnFg[t]; s_lnFb[t] = (bf16)lnFb[t];
  if (t < RHID) { s_bg1[t] = bg1[t]; s_wg1d[t] = Wg1[256*RHID + t]; }
  if (t < ROWS) { float m = mp[row0 + t]; s_diff[t] = 1.f - 2.f*fabsf(m - 0.5f); }

  // ---- stage this wave's x rows -> xfrag (per-wave slice, no barrier needed for this) ----
  {
    const float* xw = x + (size_t)arow0 * D + (lane & 15) * D + (lane >> 4) * 8;
    #pragma unroll
    for (int ks = 0; ks < 8; ++ks) {
      const float* xp = xw + ks * 32;
      float4 v0 = *reinterpret_cast<const float4*>(xp);
      float4 v1 = *reinterpret_cast<const float4*>(xp + 4);
      bf16x8 fr;
      fr[0]=(bf16)v0.x; fr[1]=(bf16)v0.y; fr[2]=(bf16)v0.z; fr[3]=(bf16)v0.w;
      fr[4]=(bf16)v1.x; fr[5]=(bf16)v1.y; fr[6]=(bf16)v1.z; fr[7]=(bf16)v1.w;
      *reinterpret_cast<bf16x8*>(&rA[(ks*64 + lane)*8]) = fr;
    }
  }
  __syncthreads();   // the ONLY barrier: shared constants ready

  // ---- GEMM1: Q16x128 = X(16x256) * Wq(256x128 all heads) ----
  {
    f32x4 acc1[8];
    #pragma unroll
    for (int n = 0; n < 8; ++n) acc1[n] = (f32x4)0.f;
    const bf16x8* pQ = reinterpret_cast<const bf16x8*>(ws + OFF_Q);
    #pragma unroll
    for (int ks = 0; ks < 8; ++ks) {
      bf16x8 a = *reinterpret_cast<const bf16x8*>(&rA[(ks*64 + lane)*8]);
      #pragma unroll
      for (int n = 0; n < 8; ++n) {   // n = h*2 + nt
        bf16x8 b = pQ[(((n >> 1)*8 + ks)*2 + (n & 1))*64 + lane];
        acc1[n] = MFMA16(a, b, acc1[n]);
      }
    }
    // write q (swizzled) into rA[0..2048)
    #pragma unroll
    for (int n = 0; n < 8; ++n) {
      float bqv = (float)s_bq[n*16 + lc];
      #pragma unroll
      for (int r = 0; r < 4; ++r) {
        int rr = lr*4 + r;
        int c = n*16 + lc;
        rA[rr*128 + (c ^ ((rr & 7) << 3))] = (bf16)(acc1[n][r] + bqv);
      }
    }
  }

  // ---- attention: lane = (row r16, head h) ----
  {
    const int r16 = lane & 15, h = lane >> 4;
    const int swr = (r16 & 7) << 3;
    float q[32];
    #pragma unroll
    for (int g = 0; g < 4; ++g) {
      bf16x8 v = *reinterpret_cast<const bf16x8*>(&rA[r16*128 + ((h*32 + g*8) ^ swr)]);
      #pragma unroll
      for (int j = 0; j < 8; ++j) q[g*8 + j] = (float)v[j];
    }
    float u = s_diff[w*16 + r16];
    float up = u + 1e-8f;
    float mod = 1.f + s_fa[h]*up*up*s_ft[h];
    float sc[4];
    #pragma unroll
    for (int p = 0; p < 4; ++p) {
      float s = s_imp[h*4 + p];
      const float4* kp = reinterpret_cast<const float4*>(&s_pk[(h*4 + p)*32]);
      #pragma unroll
      for (int g = 0; g < 8; ++g) {
        float4 kv = kp[g];
        s = fmaf(q[g*4+0], kv.x, s); s = fmaf(q[g*4+1], kv.y, s);
        s = fmaf(q[g*4+2], kv.z, s); s = fmaf(q[g*4+3], kv.w, s);
      }
      sc[p] = s * mod * SCALE_F;
    }
    float mx = fmaxf(fmaxf(sc[0], sc[1]), fmaxf(sc[2], sc[3]));
    float e0 = fast_exp(sc[0]-mx), e1 = fast_exp(sc[1]-mx);
    float e2 = fast_exp(sc[2]-mx), e3 = fast_exp(sc[3]-mx);
    float inv = fast_rcp(e0+e1+e2+e3);
    e0 *= inv; e1 *= inv; e2 *= inv; e3 *= inv;
    const float4* p0 = reinterpret_cast<const float4*>(&s_pv[(h*4+0)*32]);
    const float4* p1 = reinterpret_cast<const float4*>(&s_pv[(h*4+1)*32]);
    const float4* p2 = reinterpret_cast<const float4*>(&s_pv[(h*4+2)*32]);
    const float4* p3 = reinterpret_cast<const float4*>(&s_pv[(h*4+3)*32]);
    #pragma unroll
    for (int kg = 0; kg < 4; ++kg) {
      float4 a0 = p0[kg*2],   b0v = p0[kg*2+1];
      float4 a1 = p1[kg*2],   b1v = p1[kg*2+1];
      float4 a2 = p2[kg*2],   b2v = p2[kg*2+1];
      float4 a3 = p3[kg*2],   b3v = p3[kg*2+1];
      bf16x8 av;
      av[0] = (bf16)(e0*a0.x + e1*a1.x + e2*a2.x + e3*a3.x);
      av[1] = (bf16)(e0*a0.y + e1*a1.y + e2*a2.y + e3*a3.y);
      av[2] = (bf16)(e0*a0.z + e1*a1.z + e2*a2.z + e3*a3.z);
      av[3] = (bf16)(e0*a0.w + e1*a1.w + e2*a2.w + e3*a3.w);
      av[4] = (bf16)(e0*b0v.x + e1*b1v.x + e2*b2v.x + e3*b3v.x);
      av[5] = (bf16)(e0*b0v.y + e1*b1v.y + e2*b2v.y + e3*b3v.y);
      av[6] = (bf16)(e0*b0v.z + e1*b1v.z + e2*b2v.z + e3*b3v.z);
      av[7] = (bf16)(e0*b0v.w + e1*b1v.w + e2*b2v.w + e3*b3v.w);
      // attfrag[h][slot kg*16+r16][j] at rA[2048..4096)
      *reinterpret_cast<bf16x8*>(&rA[2048 + h*512 + (kg*16 + r16)*8]) = av;
    }
  }

  // ---- Wo GEMM (per head, M=16,K=32,N=32) + per-head LN -> combfrag rA[0..2048) ----
  {
    const bf16x8* pO = reinterpret_cast<const bf16x8*>(ws + OFF_O);
    #pragma unroll
    for (int h = 0; h < 4; ++h) {
      bf16x8 a = *reinterpret_cast<const bf16x8*>(&rA[2048 + h*512 + lane*8]);
      f32x4 o0 = MFMA16(a, pO[(h*2 + 0)*64 + lane], (f32x4)0.f);
      f32x4 o1 = MFMA16(a, pO[(h*2 + 1)*64 + lane], (f32x4)0.f);
      float bo0 = (float)s_bo[h*32 + lc],  bo1 = (float)s_bo[h*32 + 16 + lc];
      float lg0 = (float)s_lng[h*32 + lc], lg1 = (float)s_lng[h*32 + 16 + lc];
      float lb0 = (float)s_lnb[h*32 + lc], lb1 = (float)s_lnb[h*32 + 16 + lc];
      #pragma unroll
      for (int r = 0; r < 4; ++r) {
        float v0 = o0[r] + bo0;
        float v1 = o1[r] + bo1;
        float s = v0 + v1, sq = v0*v0 + v1*v1;
        s += __shfl_xor(s, 1, 64);  sq += __shfl_xor(sq, 1, 64);
        s += __shfl_xor(s, 2, 64);  sq += __shfl_xor(sq, 2, 64);
        s += __shfl_xor(s, 4, 64);  sq += __shfl_xor(sq, 4, 64);
        s += __shfl_xor(s, 8, 64);  sq += __shfl_xor(sq, 8, 64);
        float mean = s * (1.f/32.f);
        float var  = sq * (1.f/32.f) - mean*mean;
        float rstd = rsqrtf(var + 1e-5f);
        float n0 = (v0 - mean)*rstd*lg0 + lb0;
        float n1 = (v1 - mean)*rstd*lg1 + lb1;
        int rr = lr*4 + r;
        // combfrag: c = h*32 + o ; ks = h ; slot = kg*16+rr ; j = o&7
        rA[h*512 + (((lc >> 3))*16 + rr)*8 + (lc & 7)]     = (bf16)n0;  // o = lc
        rA[h*512 + ((2 + (lc >> 3))*16 + rr)*8 + (lc & 7)] = (bf16)n1;  // o = 16+lc
      }
    }
  }

  // ---- GEMM2: out_pre 16x256 = combined(16x128) * Wf(128x256) ----
  f32x4 acc2[16];
  {
    #pragma unroll
    for (int n = 0; n < 16; ++n) acc2[n] = (f32x4)0.f;
    const bf16x8* pF = reinterpret_cast<const bf16x8*>(ws + OFF_F);
    #pragma unroll
    for (int ks = 0; ks < 4; ++ks) {
      bf16x8 a = *reinterpret_cast<const bf16x8*>(&rA[ks*512 + lane*8]);
      #pragma unroll
      for (int nt = 0; nt < 16; ++nt) {
        bf16x8 b = pF[(ks*16 + nt)*64 + lane];
        acc2[nt] = MFMA16(a, b, acc2[nt]);
      }
    }
    #pragma unroll
    for (int nt = 0; nt < 16; ++nt) {
      float bfv = (float)s_bf[nt*16 + lc];
      #pragma unroll
      for (int r = 0; r < 4; ++r) acc2[nt][r] += bfv;
    }
    // opfrag write (full rA)
    #pragma unroll
    for (int nt = 0; nt < 16; ++nt)
      #pragma unroll
      for (int r = 0; r < 4; ++r) {
        int rr = lr*4 + r;
        rA[((nt >> 1)*64 + (((nt & 1)*2 + (lc >> 3))*16 + rr))*8 + (lc & 7)] = (bf16)acc2[nt][r];
      }
  }

  // ---- GEMM3: hidden = relu(out_pre(16x256)*Wg1(256x64) + bg1 + diff*wg1d) -> hfrag rA[0..1024) ----
  {
    f32x4 acc3[4];
    #pragma unroll
    for (int n = 0; n < 4; ++n) acc3[n] = (f32x4)0.f;
    const bf16x8* pG1 = reinterpret_cast<const bf16x8*>(ws + OFF_G1);
    #pragma unroll
    for (int ks = 0; ks < 8; ++ks) {
      bf16x8 a = *reinterpret_cast<const bf16x8*>(&rA[(ks*64 + lane)*8]);
      #pragma unroll
      for (int nt = 0; nt < 4; ++nt) {
        bf16x8 b = pG1[(ks*4 + nt)*64 + lane];
        acc3[nt] = MFMA16(a, b, acc3[nt]);
      }
    }
    float dfr[4];
    #pragma unroll
    for (int r = 0; r < 4; ++r) dfr[r] = s_diff[w*16 + lr*4 + r];
    #pragma unroll
    for (int nt = 0; nt < 4; ++nt) {
      int col3 = nt*16 + lc;
      float b1v = s_bg1[col3], wdv = s_wg1d[col3];
      #pragma unroll
      for (int r = 0; r < 4; ++r) {
        int rr = lr*4 + r;
        float hv = fmaxf(acc3[nt][r] + b1v + dfr[r]*wdv, 0.f);
        rA[((nt >> 1)*64 + (((nt & 1)*2 + (lc >> 3))*16 + rr))*8 + (lc & 7)] = (bf16)hv;
      }
    }
  }

  // ---- GEMM4 (two 8-nt halves): gate = sigmoid(hidden(16x64)*Wg2(64x256)+bg2); acc2 = out_pre*gate + x ----
  {
    const float* xr = x + (size_t)arow0 * D;
    const bf16x8* pG2 = reinterpret_cast<const bf16x8*>(ws + OFF_G2);
    #pragma unroll
    for (int half = 0; half < 2; ++half) {
      f32x4 acc4[8];
      #pragma unroll
      for (int n = 0; n < 8; ++n) acc4[n] = (f32x4)0.f;
      #pragma unroll
      for (int ks = 0; ks < 2; ++ks) {
        bf16x8 a = *reinterpret_cast<const bf16x8*>(&rA[(ks*64 + lane)*8]);
        #pragma unroll
        for (int n2 = 0; n2 < 8; ++n2) {
          bf16x8 b = pG2[(ks*16 + half*8 + n2)*64 + lane];
          acc4[n2] = MFMA16(a, b, acc4[n2]);
        }
      }
      #pragma unroll
      for (int n2 = 0; n2 < 8; ++n2) {
        int nt = half*8 + n2;
        int c = nt*16 + lc;
        float bg2v = (float)s_bg2[c];
        #pragma unroll
        for (int r = 0; r < 4; ++r) {
          int rr = lr*4 + r;
          float z = acc4[n2][r] + bg2v;
          float gate = fast_rcp(1.f + fast_exp(-z));
          acc2[nt][r] = acc2[nt][r]*gate + xr[rr*D + c];
        }
      }
    }
  }

  // ---- final LN (per row over 256 cols; 16-lane shfl groups, no LDS) + store ----
  {
    float* obase = out + (size_t)arow0 * D;
    #pragma unroll
    for (int r = 0; r < 4; ++r) {
      float s = 0.f, sq = 0.f;
      #pragma unroll
      for (int nt = 0; nt < 16; ++nt) {
        float v = acc2[nt][r];
        s += v; sq = fmaf(v, v, sq);
      }
      s += __shfl_xor(s, 1, 64);  sq += __shfl_xor(sq, 1, 64);
      s += __shfl_xor(s, 2, 64);  sq += __shfl_xor(sq, 2, 64);
      s += __shfl_xor(s, 4, 64);  sq += __shfl_xor(sq, 4, 64);
      s += __shfl_xor(s, 8, 64);  sq += __shfl_xor(sq, 8, 64);
      float mean = s * (1.f/256.f);
      float var  = sq * (1.f/256.f) - mean*mean;
      float rstd = rsqrtf(var + 1e-5f);
      int rr = lr*4 + r;
      #pragma unroll
      for (int nt = 0; nt < 16; ++nt) {
        int c = nt*16 + lc;
        obase[rr*D + c] = (acc2[nt][r] - mean)*rstd*(float)s_lnFg[c] + (float)s_lnFb[c];
      }
    }
  }
}

extern "C" void kernel_launch(void* const* d_in, const int* in_sizes, int n_in,
                              void* d_out, int out_size, void* d_ws, size_t ws_size,
                              hipStream_t stream) {
  (void)in_sizes; (void)n_in; (void)ws_size; (void)out_size;
  const float* x   = (const float*)d_in[0];
  const float* mp  = (const float*)d_in[1];
  const float* Wq  = (const float*)d_in[2];
  const float* bq  = (const float*)d_in[3];
  const float* pk  = (const float*)d_in[4];
  const float* pv  = (const float*)d_in[5];
  const float* imp = (const float*)d_in[6];
  const float* fa  = (const float*)d_in[7];
  const float* ft  = (const float*)d_in[8];
  const float* Wo  = (const float*)d_in[9];
  const float* bo  = (const float*)d_in[10];
  const float* lng = (const float*)d_in[11];
  const float* lnb = (const float*)d_in[12];
  const float* Wf  = (const float*)d_in[13];
  const float* bf  = (const float*)d_in[14];
  const float* Wg1 = (const float*)d_in[15];
  const float* bg1 = (const float*)d_in[16];
  const float* Wg2 = (const float*)d_in[17];
  const float* bg2 = (const float*)d_in[18];
  const float* lnFg= (const float*)d_in[19];
  const float* lnFb= (const float*)d_in[20];
  float* out = (float*)d_out;
  bf16* ws = (bf16*)d_ws;

  hipLaunchKernelGGL(prep_kernel, dim3((NPACK + 255)/256), dim3(256), 0, stream,
                     Wq, Wf, Wg1, Wg2, Wo, ws);
  hipLaunchKernelGGL(faiia_kernel, dim3(NROWS_TOT / ROWS), dim3(256), 0, stream,
                     x, mp, bq, pk, pv, imp, fa, ft, bo, lng, lnb,
                     bf, Wg1, bg1, bg2, lnFg, lnFb, ws, out);
}

// Round 9
// 244.031 us; speedup vs baseline: 1.7852x; 1.7852x over previous
//
#include <hip/hip_runtime.h>
#include <math.h>

typedef __bf16 bf16;
typedef __bf16 bf16x8 __attribute__((ext_vector_type(8)));
typedef float f32x4 __attribute__((ext_vector_type(4)));

#define MFMA16(a,b,c) __builtin_amdgcn_mfma_f32_16x16x32_bf16((a),(b),(c),0,0,0)

#define D 256
#define H 4
#define A 32
#define P 4
#define HA 128
#define RHID 64
#define ROWS 64
#define NROWS_TOT 262144
#define SCALE_F 0.17677669529663687f

// ws offsets in bf16 elements
#define OFF_Q  0
#define OFF_F  32768
#define OFF_G1 65536
#define OFF_G2 81920
#define OFF_O  98304
#define NPACK  102400

__device__ __forceinline__ float fast_exp(float x) { return __expf(x); }
__device__ __forceinline__ float fast_rcp(float x) { return __builtin_amdgcn_rcpf(x); }

// ---------------- weight prepack: f32 -> bf16 in MFMA B-fragment order ----------------
// B-fragment for 16x16x32: lane l holds col n = l&15, k = (l>>4)*8 + j (j=0..7, contiguous)
__global__ __launch_bounds__(256)
void prep_kernel(const float* __restrict__ Wq, const float* __restrict__ Wf,
                 const float* __restrict__ Wg1, const float* __restrict__ Wg2,
                 const float* __restrict__ Wo, bf16* __restrict__ ws)
{
  int i = blockIdx.x * 256 + threadIdx.x;
  if (i >= NPACK) return;
  float v;
  if (i < OFF_F) {              // packQ [h(4)][ks(8)][nt(2)][l(64)][j(8)], K=256,N=32 per head
    int j = i & 7, l = (i >> 3) & 63, nt = (i >> 9) & 1, ks = (i >> 10) & 7, h = i >> 13;
    int k = ks * 32 + (l >> 4) * 8 + j, n = nt * 16 + (l & 15);
    v = Wq[(h * 256 + k) * 32 + n];
  } else if (i < OFF_G1) {      // packF [ks(4)][gnt(16)][l][j], K=128,N=256
    int ii = i - OFF_F;
    int j = ii & 7, l = (ii >> 3) & 63, g = (ii >> 9) & 15, ks = ii >> 13;
    int k = ks * 32 + (l >> 4) * 8 + j, n = g * 16 + (l & 15);
    v = Wf[k * 256 + n];
  } else if (i < OFF_G2) {      // packG1 [ks(8)][nt(4)][l][j], K=256,N=64 (row 256 added via s_wg1d)
    int ii = i - OFF_G1;
    int j = ii & 7, l = (ii >> 3) & 63, nt = (ii >> 9) & 3, ks = ii >> 11;
    int k = ks * 32 + (l >> 4) * 8 + j, n = nt * 16 + (l & 15);
    v = Wg1[k * 64 + n];
  } else if (i < OFF_O) {       // packG2 [ks(2)][gnt(16)][l][j], K=64,N=256
    int ii = i - OFF_G2;
    int j = ii & 7, l = (ii >> 3) & 63, g = (ii >> 9) & 15, ks = ii >> 13;
    int k = ks * 32 + (l >> 4) * 8 + j, n = g * 16 + (l & 15);
    v = Wg2[k * 256 + n];
  } else {                      // packO [h(4)][nt(2)][l][j], K=32,N=32 per head
    int ii = i - OFF_O;
    int j = ii & 7, l = (ii >> 3) & 63, nt = (ii >> 9) & 1, h = ii >> 10;
    int k = (l >> 4) * 8 + j, n = nt * 16 + (l & 15);
    v = Wo[(h * 32 + k) * 32 + n];
  }
  ws[i] = (bf16)v;
}

// ---------------- fused main kernel: 64 rows/block, 4 waves, N-partitioned weights ----------------
// 6 barriers: GEMM1 -> q -> attention -> Wo is intra-wave (wave w owns head w).
// s_comb is 8192 bf16 (16KB: slots (w*4+mt) in [0,16)) -- R8's [4096] was an LDS overflow.
// s_hf ALIASES s_comb (combfrag last read before B4; hfrag written after B4).
// LDS ~75.6KB -> 2 blocks/CU; __launch_bounds__(256,2) -> VGPR 128, no spills.
__global__ __launch_bounds__(256, 2)
void faiia_kernel(const float* __restrict__ x, const float* __restrict__ mp,
    const float* __restrict__ bq, const float* __restrict__ pk,
    const float* __restrict__ pv, const float* __restrict__ imp,
    const float* __restrict__ fa, const float* __restrict__ ft,
    const float* __restrict__ bo, const float* __restrict__ lng,
    const float* __restrict__ lnb, const float* __restrict__ bfb,
    const float* __restrict__ Wg1, const float* __restrict__ bg1,
    const float* __restrict__ bg2, const float* __restrict__ lnFg,
    const float* __restrict__ lnFb, const bf16* __restrict__ ws,
    float* __restrict__ out)
{
  // s_xop (32KB): xfrag [mt4][ks8][64][8] -> attfrag [h4][mt4][64][8] (lower 16KB)
  //               -> opfrag [ks8][64][8 per slot-group] (full 32KB)
  __shared__ __attribute__((aligned(16))) bf16 s_xop[16384];
  __shared__ __attribute__((aligned(16))) bf16 s_q[8192];     // q 64x128, XOR-swizzled
  __shared__ __attribute__((aligned(16))) bf16 s_comb[8192];  // combined frag [ks4][mt4][64][8]; hfrag aliases [0:4096)
  __shared__ float s_lnsum[256], s_lnsq[256];
  __shared__ float s_pk[H*P*A], s_pv[H*P*A], s_imp[H*P], s_fa[H], s_ft[H];
  __shared__ bf16 s_bq[HA], s_bo[HA], s_lng[HA], s_lnb[HA];
  __shared__ bf16 s_bf[D], s_bg2[D], s_lnFg[D], s_lnFb[D];
  __shared__ float s_bg1[RHID], s_wg1d[RHID];
  __shared__ float s_diff[ROWS];

  bf16* s_hf = s_comb;            // alias: hidden frag [ks2][mt4][64][8] (4096 bf16)

  const int t = threadIdx.x;
  const int lane = t & 63;
  const int w = t >> 6;           // wave id (= head id in phases 1-3)
  const int lr = lane >> 4;       // row-group 0..3
  const int lc = lane & 15;       // col-in-tile
  const int row0 = blockIdx.x * ROWS;

  // ---- stage small constants ----
  for (int i = t; i < H*P*A; i += 256) { s_pk[i] = pk[i]; s_pv[i] = pv[i]; }
  if (t < H*P) s_imp[t] = imp[t];
  if (t < H) { s_fa[t] = fa[t]; s_ft[t] = ft[t]; }
  if (t < HA) { s_bq[t] = (bf16)bq[t]; s_bo[t] = (bf16)bo[t];
                s_lng[t] = (bf16)lng[t]; s_lnb[t] = (bf16)lnb[t]; }
  s_bf[t] = (bf16)bfb[t]; s_bg2[t] = (bf16)bg2[t];
  s_lnFg[t] = (bf16)lnFg[t]; s_lnFb[t] = (bf16)lnFb[t];
  if (t < RHID) { s_bg1[t] = bg1[t]; s_wg1d[t] = Wg1[256*RHID + t]; }
  if (t < ROWS) { float m = mp[row0 + t]; s_diff[t] = 1.f - 2.f*fabsf(m - 0.5f); }

  // ---- stage x -> bf16 A-fragments: slot s = (mt*8+ks)*64 + l ----
  {
    const float* xbase = x + (size_t)row0 * D;
    #pragma unroll
    for (int i = 0; i < 8; ++i) {
      int s = t + 256*i;
      int l = s & 63, ks = (s >> 6) & 7, mt = s >> 9;
      int row = mt*16 + (l & 15);
      int k0 = ks*32 + ((l >> 4) & 3)*8;
      const float* xp = xbase + row*D + k0;
      float4 v0 = *reinterpret_cast<const float4*>(xp);
      float4 v1 = *reinterpret_cast<const float4*>(xp + 4);
      bf16x8 fr;
      fr[0]=(bf16)v0.x; fr[1]=(bf16)v0.y; fr[2]=(bf16)v0.z; fr[3]=(bf16)v0.w;
      fr[4]=(bf16)v1.x; fr[5]=(bf16)v1.y; fr[6]=(bf16)v1.z; fr[7]=(bf16)v1.w;
      *reinterpret_cast<bf16x8*>(&s_xop[(size_t)s * 8]) = fr;
    }
  }
  __syncthreads();   // B1: xfrag + constants ready

  // ---- GEMM1: Q = X(64x256) * Wq[head=w](256x32); q -> s_q (own region) ----
  bf16x8 woB0, woB1;   // Wo B-fragments, prefetched early
  {
    const bf16x8* pO = reinterpret_cast<const bf16x8*>(ws + OFF_O);
    woB0 = pO[(w*2 + 0)*64 + lane];
    woB1 = pO[(w*2 + 1)*64 + lane];
    f32x4 acc[4][2];
    #pragma unroll
    for (int mt = 0; mt < 4; ++mt) { acc[mt][0] = (f32x4)0.f; acc[mt][1] = (f32x4)0.f; }
    const bf16x8* pQ = reinterpret_cast<const bf16x8*>(ws + OFF_Q);
    #pragma unroll
    for (int ks = 0; ks < 8; ++ks) {
      bf16x8 b0 = pQ[((w*8 + ks)*2 + 0)*64 + lane];
      bf16x8 b1 = pQ[((w*8 + ks)*2 + 1)*64 + lane];
      #pragma unroll
      for (int mt = 0; mt < 4; ++mt) {
        bf16x8 a = *reinterpret_cast<const bf16x8*>(&s_xop[((mt*8 + ks)*64 + lane)*8]);
        acc[mt][0] = MFMA16(a, b0, acc[mt][0]);
        acc[mt][1] = MFMA16(a, b1, acc[mt][1]);
      }
    }
    float bq0 = (float)s_bq[w*32 + lc], bq1 = (float)s_bq[w*32 + 16 + lc];
    #pragma unroll
    for (int mt = 0; mt < 4; ++mt)
      #pragma unroll
      for (int r = 0; r < 4; ++r) {
        int row = mt*16 + lr*4 + r;
        int sw = (row & 7) << 3;                 // XOR swizzle (bf16 elements)
        int c0 = (w*32 + lc) ^ sw;
        int c1 = (w*32 + 16 + lc) ^ sw;
        s_q[row*128 + c0] = (bf16)(acc[mt][0][r] + bq0);
        s_q[row*128 + c1] = (bf16)(acc[mt][1][r] + bq1);
      }
  }
  __syncthreads();   // B2: q ready (cross-wave via swizzle) + all xfrag reads done

  // ---- Phase B: prototype attention; wave w = head w, lane = row ----
  {
    const int r = lane;
    const int h = w;
    const int swr = (r & 7) << 3;
    float q[32];
    #pragma unroll
    for (int g = 0; g < 4; ++g) {
      bf16x8 v = *reinterpret_cast<const bf16x8*>(&s_q[r*128 + ((h*32 + g*8) ^ swr)]);
      #pragma unroll
      for (int j = 0; j < 8; ++j) q[g*8 + j] = (float)v[j];
    }
    float u = s_diff[r];
    float up = u + 1e-8f;
    float mod = 1.f + s_fa[h]*up*up*s_ft[h];
    float sc[4];
    #pragma unroll
    for (int p = 0; p < 4; ++p) {
      float s = s_imp[h*4 + p];
      const float4* kp = reinterpret_cast<const float4*>(&s_pk[(h*4 + p)*32]);
      #pragma unroll
      for (int g = 0; g < 8; ++g) {
        float4 kv = kp[g];
        s = fmaf(q[g*4+0], kv.x, s); s = fmaf(q[g*4+1], kv.y, s);
        s = fmaf(q[g*4+2], kv.z, s); s = fmaf(q[g*4+3], kv.w, s);
      }
      sc[p] = s * mod * SCALE_F;
    }
    float mx = fmaxf(fmaxf(sc[0], sc[1]), fmaxf(sc[2], sc[3]));
    float e0 = fast_exp(sc[0]-mx), e1 = fast_exp(sc[1]-mx);
    float e2 = fast_exp(sc[2]-mx), e3 = fast_exp(sc[3]-mx);
    float inv = fast_rcp(e0+e1+e2+e3);
    e0 *= inv; e1 *= inv; e2 *= inv; e3 *= inv;
    const float4* p0 = reinterpret_cast<const float4*>(&s_pv[(h*4+0)*32]);
    const float4* p1 = reinterpret_cast<const float4*>(&s_pv[(h*4+1)*32]);
    const float4* p2 = reinterpret_cast<const float4*>(&s_pv[(h*4+2)*32]);
    const float4* p3 = reinterpret_cast<const float4*>(&s_pv[(h*4+3)*32]);
    const int mt = r >> 4, rl = r & 15;
    #pragma unroll
    for (int g = 0; g < 4; ++g) {
      float4 a0 = p0[g*2],   b0v = p0[g*2+1];
      float4 a1 = p1[g*2],   b1v = p1[g*2+1];
      float4 a2 = p2[g*2],   b2v = p2[g*2+1];
      float4 a3 = p3[g*2],   b3v = p3[g*2+1];
      bf16x8 av;
      av[0] = (bf16)(e0*a0.x + e1*a1.x + e2*a2.x + e3*a3.x);
      av[1] = (bf16)(e0*a0.y + e1*a1.y + e2*a2.y + e3*a3.y);
      av[2] = (bf16)(e0*a0.z + e1*a1.z + e2*a2.z + e3*a3.z);
      av[3] = (bf16)(e0*a0.w + e1*a1.w + e2*a2.w + e3*a3.w);
      av[4] = (bf16)(e0*b0v.x + e1*b1v.x + e2*b2v.x + e3*b3v.x);
      av[5] = (bf16)(e0*b0v.y + e1*b1v.y + e2*b2v.y + e3*b3v.y);
      av[6] = (bf16)(e0*b0v.z + e1*b1v.z + e2*b2v.z + e3*b3v.z);
      av[7] = (bf16)(e0*b0v.w + e1*b1v.w + e2*b2v.w + e3*b3v.w);
      // attfrag[h][mt][g*16+rl][j] in lower 16KB of s_xop (wave-local: h == w)
      *reinterpret_cast<bf16x8*>(&s_xop[(((h*4) + mt)*64 + g*16 + rl)*8]) = av;
    }
  }
  // no barrier: Wo reads wave-local attfrag (same-wave DS ordering)

  // ---- Wo-GEMM + per-head LN; wave w = head w; writes combfrag -> s_comb ----
  {
    f32x4 acc[4][2];
    #pragma unroll
    for (int mt = 0; mt < 4; ++mt) { acc[mt][0] = (f32x4)0.f; acc[mt][1] = (f32x4)0.f; }
    #pragma unroll
    for (int mt = 0; mt < 4; ++mt) {
      bf16x8 a = *reinterpret_cast<const bf16x8*>(&s_xop[((w*4 + mt)*64 + lane)*8]);
      acc[mt][0] = MFMA16(a, woB0, acc[mt][0]);
      acc[mt][1] = MFMA16(a, woB1, acc[mt][1]);
    }
    float bo0 = (float)s_bo[w*32 + lc],  bo1 = (float)s_bo[w*32 + 16 + lc];
    float lg0 = (float)s_lng[w*32 + lc], lg1 = (float)s_lng[w*32 + 16 + lc];
    float lb0 = (float)s_lnb[w*32 + lc], lb1 = (float)s_lnb[w*32 + 16 + lc];
    #pragma unroll
    for (int mt = 0; mt < 4; ++mt)
      #pragma unroll
      for (int r = 0; r < 4; ++r) {
        float v0 = acc[mt][0][r] + bo0;
        float v1 = acc[mt][1][r] + bo1;
        float s = v0 + v1, sq = v0*v0 + v1*v1;
        s += __shfl_xor(s, 1, 64);  sq += __shfl_xor(sq, 1, 64);
        s += __shfl_xor(s, 2, 64);  sq += __shfl_xor(sq, 2, 64);
        s += __shfl_xor(s, 4, 64);  sq += __shfl_xor(sq, 4, 64);
        s += __shfl_xor(s, 8, 64);  sq += __shfl_xor(sq, 8, 64);
        float mean = s * (1.f/32.f);
        float var  = sq * (1.f/32.f) - mean*mean;
        float rstd = rsqrtf(var + 1e-5f);
        float n0 = (v0 - mean)*rstd*lg0 + lb0;
        float n1 = (v1 - mean)*rstd*lg1 + lb1;
        int rl = lr*4 + r;
        // combfrag[ks=w][mt][slot][j]: combined col = w*32 + o ; slot = 16*(o>>3)+rl ; j = o&7
        s_comb[((w*4 + mt)*64 + 16*(lc >> 3)       + rl)*8 + (lane & 7)] = (bf16)n0;
        s_comb[((w*4 + mt)*64 + 16*(2 + (lc >> 3)) + rl)*8 + (lane & 7)] = (bf16)n1;
      }
  }
  __syncthreads();   // B3: combfrag ready

  // ---- GEMM2: out_pre = combined(64x128) * Wf(128x256); wave w -> cols [64w,64w+64) ----
  f32x4 acc2[4][4];
  {
    #pragma unroll
    for (int mt = 0; mt < 4; ++mt)
      #pragma unroll
      for (int nt = 0; nt < 4; ++nt) acc2[mt][nt] = (f32x4)0.f;
    const bf16x8* pF = reinterpret_cast<const bf16x8*>(ws + OFF_F);
    #pragma unroll
    for (int ks = 0; ks < 4; ++ks) {
      bf16x8 a[4], bb[4];
      #pragma unroll
      for (int mt = 0; mt < 4; ++mt)
        a[mt] = *reinterpret_cast<const bf16x8*>(&s_comb[((ks*4 + mt)*64 + lane)*8]);
      #pragma unroll
      for (int nt = 0; nt < 4; ++nt)
        bb[nt] = pF[(ks*16 + w*4 + nt)*64 + lane];
      #pragma unroll
      for (int mt = 0; mt < 4; ++mt)
        #pragma unroll
        for (int nt = 0; nt < 4; ++nt)
          acc2[mt][nt] = MFMA16(a[mt], bb[nt], acc2[mt][nt]);
    }
    #pragma unroll
    for (int nt = 0; nt < 4; ++nt) {
      float bfv = (float)s_bf[w*64 + nt*16 + lc];
      #pragma unroll
      for (int mt = 0; mt < 4; ++mt)
        #pragma unroll
        for (int r = 0; r < 4; ++r) acc2[mt][nt][r] += bfv;
    }
    // opfrag write into s_xop (xfrag reads done pre-B2, attfrag reads done pre-B3)
    #pragma unroll
    for (int mt = 0; mt < 4; ++mt)
      #pragma unroll
      for (int nt = 0; nt < 4; ++nt) {
        int ks3 = w*2 + (nt >> 1);
        #pragma unroll
        for (int r = 0; r < 4; ++r) {
          int lane2 = 16*((nt & 1)*2 + (lc >> 3)) + (lr*4 + r);
          s_xop[((ks3*4 + mt)*64 + lane2)*8 + (lane & 7)] = (bf16)acc2[mt][nt][r];
        }
      }
  }
  __syncthreads();   // B4: opfrag ready (also: all combfrag reads done -> hfrag alias safe)

  // ---- GEMM3: hidden = relu(out_pre(64x256)*Wg1(256x64) + diff*wg1d + bg1); wave w -> cols [16w,16w+16) ----
  {
    f32x4 acc3[4];
    #pragma unroll
    for (int mt = 0; mt < 4; ++mt) acc3[mt] = (f32x4)0.f;
    const bf16x8* pG1 = reinterpret_cast<const bf16x8*>(ws + OFF_G1);
    #pragma unroll
    for (int ks = 0; ks < 8; ++ks) {
      bf16x8 b = pG1[(ks*4 + w)*64 + lane];
      #pragma unroll
      for (int mt = 0; mt < 4; ++mt) {
        bf16x8 a = *reinterpret_cast<const bf16x8*>(&s_xop[((ks*4 + mt)*64 + lane)*8]);
        acc3[mt] = MFMA16(a, b, acc3[mt]);
      }
    }
    int col3 = w*16 + lc;
    float b1v = s_bg1[col3], wdv = s_wg1d[col3];
    #pragma unroll
    for (int mt = 0; mt < 4; ++mt)
      #pragma unroll
      for (int r = 0; r < 4; ++r) {
        int row = mt*16 + lr*4 + r;
        float hv = fmaxf(acc3[mt][r] + b1v + s_diff[row]*wdv, 0.f);
        s_hf[(((w >> 1)*4 + mt)*64 + 16*((w & 1)*2 + (lc >> 3)) + (lr*4 + r))*8 + (lane & 7)] = (bf16)hv;
      }
  }
  __syncthreads();   // B5: hfrag ready

  // ---- GEMM4 (two nt-halves to cap live regs): gate = sigmoid(...); acc2 = out_pre*gate + x ----
  {
    const float* xbase = x + (size_t)row0 * D;
    const bf16x8* pG2 = reinterpret_cast<const bf16x8*>(ws + OFF_G2);
    #pragma unroll
    for (int half = 0; half < 2; ++half) {
      f32x4 acc4[4][2];
      #pragma unroll
      for (int mt = 0; mt < 4; ++mt) { acc4[mt][0] = (f32x4)0.f; acc4[mt][1] = (f32x4)0.f; }
      #pragma unroll
      for (int ks = 0; ks < 2; ++ks) {
        bf16x8 a[4], bb[2];
        #pragma unroll
        for (int mt = 0; mt < 4; ++mt)
          a[mt] = *reinterpret_cast<const bf16x8*>(&s_hf[((ks*4 + mt)*64 + lane)*8]);
        #pragma unroll
        for (int n2 = 0; n2 < 2; ++n2)
          bb[n2] = pG2[(ks*16 + w*4 + half*2 + n2)*64 + lane];
        #pragma unroll
        for (int mt = 0; mt < 4; ++mt)
          #pragma unroll
          for (int n2 = 0; n2 < 2; ++n2)
            acc4[mt][n2] = MFMA16(a[mt], bb[n2], acc4[mt][n2]);
      }
      #pragma unroll
      for (int n2 = 0; n2 < 2; ++n2) {
        int nt = half*2 + n2;
        int c = w*64 + nt*16 + lc;
        float bg2v = (float)s_bg2[c];
        #pragma unroll
        for (int mt = 0; mt < 4; ++mt)
          #pragma unroll
          for (int r = 0; r < 4; ++r) {
            int row = mt*16 + lr*4 + r;
            float z = acc4[mt][n2][r] + bg2v;
            float gate = fast_rcp(1.f + fast_exp(-z));
            acc2[mt][nt][r] = acc2[mt][nt][r]*gate + xbase[row*D + c];
          }
      }
    }
  }

  // ---- final LN partials (per row over this wave's 64 cols) ----
  {
    #pragma unroll
    for (int mt = 0; mt < 4; ++mt)
      #pragma unroll
      for (int r = 0; r < 4; ++r) {
        float s = 0.f, sq = 0.f;
        #pragma unroll
        for (int nt = 0; nt < 4; ++nt) {
          float v = acc2[mt][nt][r];
          s += v; sq = fmaf(v, v, sq);
        }
        s += __shfl_xor(s, 1, 64);  sq += __shfl_xor(sq, 1, 64);
        s += __shfl_xor(s, 2, 64);  sq += __shfl_xor(sq, 2, 64);
        s += __shfl_xor(s, 4, 64);  sq += __shfl_xor(sq, 4, 64);
        s += __shfl_xor(s, 8, 64);  sq += __shfl_xor(sq, 8, 64);
        if (lc == 0) {
          int row = mt*16 + lr*4 + r;
          s_lnsum[row*4 + w] = s;
          s_lnsq[row*4 + w]  = sq;
        }
      }
  }
  __syncthreads();   // B6: LN partials ready

  // ---- finalize LN per-lane from partials + store ----
  {
    float* obase = out + (size_t)row0 * D;
    #pragma unroll
    for (int mt = 0; mt < 4; ++mt)
      #pragma unroll
      for (int r = 0; r < 4; ++r) {
        int row = mt*16 + lr*4 + r;
        float s  = s_lnsum[row*4] + s_lnsum[row*4+1] + s_lnsum[row*4+2] + s_lnsum[row*4+3];
        float sq = s_lnsq[row*4]  + s_lnsq[row*4+1]  + s_lnsq[row*4+2]  + s_lnsq[row*4+3];
        float mean = s * (1.f/256.f);
        float var  = sq * (1.f/256.f) - mean*mean;
        float rstd = rsqrtf(var + 1e-5f);
        #pragma unroll
        for (int nt = 0; nt < 4; ++nt) {
          int c = w*64 + nt*16 + lc;
          obase[row*D + c] = (acc2[mt][nt][r] - mean)*rstd*(float)s_lnFg[c] + (float)s_lnFb[c];
        }
      }
  }
}

extern "C" void kernel_launch(void* const* d_in, const int* in_sizes, int n_in,
                              void* d_out, int out_size, void* d_ws, size_t ws_size,
                              hipStream_t stream) {
  (void)in_sizes; (void)n_in; (void)ws_size; (void)out_size;
  const float* x   = (const float*)d_in[0];
  const float* mp  = (const float*)d_in[1];
  const float* Wq  = (const float*)d_in[2];
  const float* bq  = (const float*)d_in[3];
  const float* pk  = (const float*)d_in[4];
  const float* pv  = (const float*)d_in[5];
  const float* imp = (const float*)d_in[6];
  const float* fa  = (const float*)d_in[7];
  const float* ft  = (const float*)d_in[8];
  const float* Wo  = (const float*)d_in[9];
  const float* bo  = (const float*)d_in[10];
  const float* lng = (const float*)d_in[11];
  const float* lnb = (const float*)d_in[12];
  const float* Wf  = (const float*)d_in[13];
  const float* bf  = (const float*)d_in[14];
  const float* Wg1 = (const float*)d_in[15];
  const float* bg1 = (const float*)d_in[16];
  const float* Wg2 = (const float*)d_in[17];
  const float* bg2 = (const float*)d_in[18];
  const float* lnFg= (const float*)d_in[19];
  const float* lnFb= (const float*)d_in[20];
  float* out = (float*)d_out;
  bf16* ws = (bf16*)d_ws;

  hipLaunchKernelGGL(prep_kernel, dim3((NPACK + 255)/256), dim3(256), 0, stream,
                     Wq, Wf, Wg1, Wg2, Wo, ws);
  hipLaunchKernelGGL(faiia_kernel, dim3(NROWS_TOT / ROWS), dim3(256), 0, stream,
                     x, mp, bq, pk, pv, imp, fa, ft, bo, lng, lnb,
                     bf, Wg1, bg1, bg2, lnFg, lnFb, ws, out);
}